// Round 5
// baseline (801.768 us; speedup 1.0000x reference)
//
#include <hip/hip_runtime.h>
#include <hip/hip_bf16.h>

#define NN 50000
#define EE 400000
#define NB 196  // ceil(NN/256)

typedef __bf16 bf16_8 __attribute__((ext_vector_type(8)));
typedef float f32x4 __attribute__((ext_vector_type(4)));

// ---------------------------------------------------------------- prep (fused)
// [0,1563): f2b; [1563,1691): tr0; [1691,1947): tr1; 1947: ve0; 1948: ve1;
// [1949, 1949+1563): degree count (cnt zeroed by memset before launch)
__global__ __launch_bounds__(256) void prep_kernel(
    const float* __restrict__ features, __bf16* __restrict__ fbf,
    const float* __restrict__ W0, const float* __restrict__ Wres0, __bf16* __restrict__ Bt0,
    const float* __restrict__ W1, __bf16* __restrict__ Bt1,
    const float* __restrict__ We0, const float* __restrict__ ae0, float* __restrict__ Ve0,
    const float* __restrict__ We1, const float* __restrict__ ae1, float* __restrict__ Ve1,
    const int* __restrict__ dst, int* __restrict__ cnt) {
  int b = blockIdx.x;
  int t = threadIdx.x;
  if (b < 1563) {                       // fp32 -> bf16, 8 elems/thread
    int i = b * 256 + t;
    if (i < NN * 64 / 8) {
      const float4* p = (const float4*)features + (size_t)i * 2;
      float4 a = p[0], c = p[1];
      bf16_8 v = {(__bf16)a.x, (__bf16)a.y, (__bf16)a.z, (__bf16)a.w,
                  (__bf16)c.x, (__bf16)c.y, (__bf16)c.z, (__bf16)c.w};
      *(bf16_8*)(fbf + (size_t)i * 8) = v;
    }
  } else if (b < 1563 + 128) {          // Bt0 (512x64): W0^T | Wres0^T
    int idx = (b - 1563) * 256 + t;
    int j = idx >> 6, k = idx & 63;
    float v = (j < 256) ? W0[k * 256 + j] : Wres0[k * 256 + (j - 256)];
    Bt0[idx] = (__bf16)v;
  } else if (b < 1563 + 128 + 256) {    // Bt1 (256x256) = W1^T
    int idx = (b - 1563 - 128) * 256 + t;
    int j = idx >> 8, k = idx & 255;
    Bt1[idx] = (__bf16)W1[k * 256 + j];
  } else if (b == 1947) {               // Ve0
    int f = t >> 2, h = t & 3;
    float s = 0.f;
    for (int d = 0; d < 64; ++d) s += We0[f * 256 + h * 64 + d] * ae0[h * 64 + d];
    Ve0[f * 4 + h] = s;
  } else if (b == 1948) {               // Ve1
    int f = t >> 2, h = t & 3;
    float s = 0.f;
    for (int d = 0; d < 64; ++d) s += We1[f * 256 + h * 64 + d] * ae1[h * 64 + d];
    Ve1[f * 4 + h] = s;
  } else {                              // degree count
    int e = (b - 1949) * 256 + t;
    if (e < EE) atomicAdd(&cnt[dst[e]], 1);
  }
}

// ---------------------------------------------------------------- chained scan
// One kernel: ticketed chained block prefix (196 blocks all co-resident).
// flag[b] holds prefix_inclusive(b)+1 (0 = not ready).
__global__ __launch_bounds__(256) void cscan_kernel(const int* __restrict__ cnt,
                                                    int* __restrict__ off,
                                                    int* __restrict__ cur,
                                                    int* __restrict__ ticket,
                                                    int* __restrict__ flag) {
  __shared__ int s[256];
  __shared__ int sbid, sbase;
  int t = threadIdx.x;
  if (t == 0) sbid = atomicAdd(ticket, 1);
  __syncthreads();
  int bid = sbid;
  int idx = bid * 256 + t;
  int c = (idx < NN) ? cnt[idx] : 0;
  s[t] = c;
  __syncthreads();
  for (int d = 1; d < 256; d <<= 1) {
    int v = (t >= d) ? s[t - d] : 0;
    __syncthreads();
    s[t] += v;
    __syncthreads();
  }
  if (t == 0) {
    int base = 0;
    if (bid > 0) {
      int v;
      do {
        v = __hip_atomic_load(&flag[bid - 1], __ATOMIC_ACQUIRE, __HIP_MEMORY_SCOPE_AGENT);
      } while (v == 0);
      base = v - 1;
    }
    __hip_atomic_store(&flag[bid], base + s[255] + 1, __ATOMIC_RELEASE,
                       __HIP_MEMORY_SCOPE_AGENT);
    sbase = base;
  }
  __syncthreads();
  int base = sbase;
  if (idx < NN) {
    int o = base + s[t] - c;  // exclusive
    off[idx] = o;
    cur[idx] = o;
  }
  if (idx == 0) off[NN] = EE;
}

// records src_csr[p] and eid_csr[p]
__global__ __launch_bounds__(256) void fill_kernel(const int* __restrict__ src,
                                                   const int* __restrict__ dst,
                                                   int* __restrict__ cur,
                                                   int* __restrict__ srcc,
                                                   int* __restrict__ eidc) {
  int e = blockIdx.x * 256 + threadIdx.x;
  if (e < EE) {
    int p = atomicAdd(&cur[dst[e]], 1);
    srcc[p] = src[e];
    eidc[p] = e;
  }
}

// ---------------------------------------------------------------- edge ee pass
// eeo[e*8 + {0..3}] = ef[e].Ve0 (heads), eeo[e*8 + {4..7}] = ef[e].Ve1.
// 4 lanes per row: 64B-contiguous segments per load instr; coalesced writes.
__global__ __launch_bounds__(256) void eek_kernel(const float* __restrict__ ef,
                                                  const float* __restrict__ Ve0,
                                                  const float* __restrict__ Ve1,
                                                  float* __restrict__ eeo) {
  __shared__ float V0[256], V1[256];
  V0[threadIdx.x] = Ve0[threadIdx.x];
  V1[threadIdx.x] = Ve1[threadIdx.x];
  __syncthreads();
  int r = threadIdx.x >> 2, sub = threadIdx.x & 3;
  int e = blockIdx.x * 64 + r;
  if (e >= EE) return;
  float a0 = 0, a1 = 0, a2 = 0, a3 = 0;
  float c0 = 0, c1 = 0, c2 = 0, c3 = 0;
  const float* row = ef + (size_t)e * 64 + sub * 16;
#pragma unroll
  for (int i = 0; i < 16; i += 4) {
    float4 v = *(const float4*)(row + i);
    float xs[4] = {v.x, v.y, v.z, v.w};
#pragma unroll
    for (int j = 0; j < 4; ++j) {
      float x = xs[j];
      int idx = (sub * 16 + i + j) * 4;
      a0 += x * V0[idx + 0]; a1 += x * V0[idx + 1];
      a2 += x * V0[idx + 2]; a3 += x * V0[idx + 3];
      c0 += x * V1[idx + 0]; c1 += x * V1[idx + 1];
      c2 += x * V1[idx + 2]; c3 += x * V1[idx + 3];
    }
  }
#pragma unroll
  for (int o = 1; o < 4; o <<= 1) {
    a0 += __shfl_xor(a0, o); a1 += __shfl_xor(a1, o);
    a2 += __shfl_xor(a2, o); a3 += __shfl_xor(a3, o);
    c0 += __shfl_xor(c0, o); c1 += __shfl_xor(c1, o);
    c2 += __shfl_xor(c2, o); c3 += __shfl_xor(c3, o);
  }
  if (sub == 0) {
    float4 u; u.x = a0; u.y = a1; u.z = a2; u.w = a3;
    float4 w; w.x = c0; w.y = c1; w.z = c2; w.w = c3;
    *(float4*)(eeo + (size_t)e * 8) = u;
    *(float4*)(eeo + (size_t)e * 8 + 4) = w;
  }
}

// ---------------------------------------------------------------- MFMA GEMM
// C[M x NC] = A @ B, Bt: NC x K row-major. cols<256 -> ft (bf16) + fused el/er;
// cols>=256 -> base = val + bias[col-256] (layer 0 residual).
#define LDK 40
__global__ __launch_bounds__(256) void gemm_kernel(const __bf16* __restrict__ A,
                                                   const __bf16* __restrict__ Bt,
                                                   __bf16* __restrict__ ft,
                                                   __bf16* __restrict__ base,
                                                   const float* __restrict__ bias,
                                                   const float* __restrict__ al,
                                                   const float* __restrict__ ar,
                                                   float* __restrict__ el,
                                                   float* __restrict__ er,
                                                   int M, int K) {
  __shared__ __align__(16) __bf16 Al[64 * LDK];
  __shared__ __align__(16) __bf16 Bl[64 * LDK];
  int tid = threadIdx.x;
  int wav = tid >> 6, lane = tid & 63;
  int quad = lane >> 4, l16 = lane & 15;
  int bm = blockIdx.x * 64;
  int bn = blockIdx.y * 64;
  int sr = tid >> 2;
  int sk = (tid & 3) << 3;

  f32x4 acc[4] = {{0, 0, 0, 0}, {0, 0, 0, 0}, {0, 0, 0, 0}, {0, 0, 0, 0}};

  for (int k0 = 0; k0 < K; k0 += 32) {
    uint4 av = {0, 0, 0, 0};
    int arow = bm + sr;
    if (arow < M) av = *(const uint4*)(A + (size_t)arow * K + k0 + sk);
    uint4 bv = *(const uint4*)(Bt + (size_t)(bn + sr) * K + k0 + sk);
    __syncthreads();
    *(uint4*)&Al[sr * LDK + sk] = av;
    *(uint4*)&Bl[sr * LDK + sk] = bv;
    __syncthreads();
    bf16_8 af = *(const bf16_8*)&Al[(wav * 16 + l16) * LDK + quad * 8];
#pragma unroll
    for (int nt = 0; nt < 4; ++nt) {
      bf16_8 bf = *(const bf16_8*)&Bl[(nt * 16 + l16) * LDK + quad * 8];
      acc[nt] = __builtin_amdgcn_mfma_f32_16x16x32_bf16(af, bf, acc[nt], 0, 0, 0);
    }
  }

  int row0 = bm + wav * 16 + quad * 4;

  // fused el/er for head hb = bn/64 (cols < 256 only)
  if (bn < 256) {
    int hb = bn >> 6;
#pragma unroll
    for (int r = 0; r < 4; ++r) {
      float pl = 0.f, pr = 0.f;
#pragma unroll
      for (int nt = 0; nt < 4; ++nt) {
        float v = acc[nt][r];
        int d = nt * 16 + l16;
        pl += v * al[hb * 64 + d];
        pr += v * ar[hb * 64 + d];
      }
#pragma unroll
      for (int o2 = 8; o2 > 0; o2 >>= 1) {
        pl += __shfl_xor(pl, o2);
        pr += __shfl_xor(pr, o2);
      }
      int row = row0 + r;
      if (l16 == 0 && row < M) {
        el[row * 4 + hb] = pl;
        er[row * 4 + hb] = pr;
      }
    }
  }

#pragma unroll
  for (int nt = 0; nt < 4; ++nt) {
    int col = bn + nt * 16 + l16;
#pragma unroll
    for (int r = 0; r < 4; ++r) {
      int row = row0 + r;
      if (row < M) {
        float v = acc[nt][r];
        if (col < 256)
          ft[(size_t)row * 256 + col] = (__bf16)v;
        else
          base[(size_t)row * 256 + (col - 256)] = (__bf16)(v + bias[col - 256]);
      }
    }
  }
}

// ---------------------------------------------------------------- agg
// One block per dst node; wave = head. Computes softmax weight inline:
// w = exp(leaky(el[s] + er[n] + eeo[e])) — all wave-uniform loads.
// acc += w*ft[s], den += w. LAYER 0: +prev, ELU -> outb bf16 (aliases prev;
// same-slot RMW). LAYER 1: +prev+bias, mean heads -> outf fp32.
template <int LAYER>
__global__ __launch_bounds__(256) void agg_kernel(const int* __restrict__ off,
                                                  const int* __restrict__ srcc,
                                                  const int* __restrict__ eidc,
                                                  const float* __restrict__ eeo,
                                                  const float* __restrict__ el,
                                                  const float* __restrict__ er,
                                                  const __bf16* __restrict__ ft,
                                                  const __bf16* prev,
                                                  const float* __restrict__ bias,
                                                  __bf16* outb,
                                                  float* __restrict__ outf) {
  __shared__ float red[256];
  int n = blockIdx.x;
  int t = threadIdx.x, h = t >> 6, lane = t & 63;
  int beg = off[n], end = off[n + 1];
  float pv = (float)prev[(size_t)n * 256 + t];
  float bv = (LAYER == 1) ? bias[t] : 0.f;
  float ern = er[n * 4 + h];
  int offd = h * 64 + lane;

  float acc = 0.f, den = 0.f;
  int j = beg;
  for (; j + 4 <= end; j += 4) {
    int s0 = srcc[j], s1 = srcc[j + 1], s2 = srcc[j + 2], s3 = srcc[j + 3];
    int e0 = eidc[j], e1 = eidc[j + 1], e2 = eidc[j + 2], e3 = eidc[j + 3];
    float z0 = el[s0 * 4 + h] + ern + eeo[(size_t)e0 * 8 + LAYER * 4 + h];
    float z1 = el[s1 * 4 + h] + ern + eeo[(size_t)e1 * 8 + LAYER * 4 + h];
    float z2 = el[s2 * 4 + h] + ern + eeo[(size_t)e2 * 8 + LAYER * 4 + h];
    float z3 = el[s3 * 4 + h] + ern + eeo[(size_t)e3 * 8 + LAYER * 4 + h];
    float w0 = __expf(z0 > 0.f ? z0 : 0.2f * z0);
    float w1 = __expf(z1 > 0.f ? z1 : 0.2f * z1);
    float w2 = __expf(z2 > 0.f ? z2 : 0.2f * z2);
    float w3 = __expf(z3 > 0.f ? z3 : 0.2f * z3);
    float v0 = (float)ft[(size_t)s0 * 256 + offd];
    float v1 = (float)ft[(size_t)s1 * 256 + offd];
    float v2 = (float)ft[(size_t)s2 * 256 + offd];
    float v3 = (float)ft[(size_t)s3 * 256 + offd];
    acc += w0 * v0; acc += w1 * v1; acc += w2 * v2; acc += w3 * v3;
    den += w0 + w1 + w2 + w3;
  }
  for (; j < end; ++j) {
    int s = srcc[j];
    float z = el[s * 4 + h] + ern + eeo[(size_t)eidc[j] * 8 + LAYER * 4 + h];
    float w = __expf(z > 0.f ? z : 0.2f * z);
    acc += w * (float)ft[(size_t)s * 256 + offd];
    den += w;
  }
  float res = (end > beg) ? acc / den : 0.f;

  if (LAYER == 0) {
    float v = res + pv;
    v = v > 0.f ? v : (__expf(v) - 1.0f);  // ELU
    outb[(size_t)n * 256 + t] = (__bf16)v;
  } else {
    red[t] = res + pv + bv;
    __syncthreads();
    if (t < 64)
      outf[(size_t)n * 64 + t] =
          0.25f * (red[t] + red[t + 64] + red[t + 128] + red[t + 192]);
  }
}

// ---------------------------------------------------------------- launch
extern "C" void kernel_launch(void* const* d_in, const int* in_sizes, int n_in,
                              void* d_out, int out_size, void* d_ws, size_t ws_size,
                              hipStream_t stream) {
  const float* features  = (const float*)d_in[0];
  const float* edge_feat = (const float*)d_in[1];
  const int*   src       = (const int*)d_in[2];
  const int*   dst       = (const int*)d_in[3];
  const float* W0    = (const float*)d_in[4];
  const float* We0   = (const float*)d_in[5];
  const float* al0   = (const float*)d_in[6];
  const float* ar0   = (const float*)d_in[7];
  const float* ae0   = (const float*)d_in[8];
  const float* b0    = (const float*)d_in[9];
  const float* Wres0 = (const float*)d_in[10];
  const float* W1    = (const float*)d_in[11];
  const float* We1   = (const float*)d_in[12];
  const float* al1   = (const float*)d_in[13];
  const float* ar1   = (const float*)d_in[14];
  const float* ae1   = (const float*)d_in[15];
  const float* b1    = (const float*)d_in[16];
  float* out = (float*)d_out;

  char* ws = (char*)d_ws;
  size_t o = 0;
  auto alloc = [&](size_t bytes) {
    void* p = ws + o;
    o = (o + bytes + 255) & ~(size_t)255;
    return p;
  };
  // zeroed region: cnt, ticket, flag (single memset)
  int*    cnt      = (int*)alloc((size_t)NN * 4);
  int*    ticket   = (int*)alloc(64 * 4);
  int*    flag     = (int*)alloc((size_t)NB * 4);
  size_t  zbytes   = (size_t)((char*)flag + NB * 4 - (char*)cnt);
  int*    off      = (int*)alloc((size_t)(NN + 1) * 4);
  int*    cur      = (int*)alloc((size_t)NN * 4);
  int*    srcc     = (int*)alloc((size_t)EE * 4);
  int*    eidc     = (int*)alloc((size_t)EE * 4);
  float*  eeo      = (float*)alloc((size_t)EE * 8 * 4);
  float*  el       = (float*)alloc((size_t)NN * 4 * 4);
  float*  er       = (float*)alloc((size_t)NN * 4 * 4);
  float*  Ve0      = (float*)alloc(256 * 4);
  float*  Ve1      = (float*)alloc(256 * 4);
  __bf16* Bt0      = (__bf16*)alloc((size_t)512 * 64 * 2);
  __bf16* Bt1      = (__bf16*)alloc((size_t)256 * 256 * 2);
  __bf16* fbf      = (__bf16*)alloc((size_t)NN * 64 * 2);
  __bf16* ft       = (__bf16*)alloc((size_t)NN * 256 * 2);
  __bf16* base     = (__bf16*)alloc((size_t)NN * 256 * 2);  // h1 aliases base
  __bf16* h1       = base;

  const int EB = (EE + 255) / 256;   // 1563
  const int MG = (NN + 63) / 64;     // 782

  hipMemsetAsync(cnt, 0, zbytes, stream);
  prep_kernel<<<1949 + EB, 256, 0, stream>>>(features, fbf, W0, Wres0, Bt0, W1, Bt1,
                                             We0, ae0, Ve0, We1, ae1, Ve1, dst, cnt);
  cscan_kernel<<<NB, 256, 0, stream>>>(cnt, off, cur, ticket, flag);
  fill_kernel<<<EB, 256, 0, stream>>>(src, dst, cur, srcc, eidc);
  eek_kernel<<<(EE + 63) / 64, 256, 0, stream>>>(edge_feat, Ve0, Ve1, eeo);

  // ---- layer 0
  gemm_kernel<<<dim3(MG, 8), 256, 0, stream>>>(fbf, Bt0, ft, base, b0, al0, ar0, el, er, NN, 64);
  agg_kernel<0><<<NN, 256, 0, stream>>>(off, srcc, eidc, eeo, el, er, ft, base, nullptr, h1, nullptr);

  // ---- layer 1
  gemm_kernel<<<dim3(MG, 4), 256, 0, stream>>>(h1, Bt1, ft, nullptr, nullptr, al1, ar1, el, er, NN, 256);
  agg_kernel<1><<<NN, 256, 0, stream>>>(off, srcc, eidc, eeo, el, er, ft, h1, b1, nullptr, out);
}

// Round 6
// 445.841 us; speedup vs baseline: 1.7983x; 1.7983x over previous
//
#include <hip/hip_runtime.h>
#include <hip/hip_bf16.h>

#define NN 50000
#define EE 400000
#define NB 196  // ceil(NN/256)

typedef __bf16 bf16_8 __attribute__((ext_vector_type(8)));
typedef float f32x4 __attribute__((ext_vector_type(4)));

// ---------------------------------------------------------------- prep (fused)
// [0,1563): f2b; [1563,1691): tr0; [1691,1947): tr1; 1947: ve0; 1948: ve1;
// [1949, 1949+1563): degree count (cnt zeroed by memset before launch)
__global__ __launch_bounds__(256) void prep_kernel(
    const float* __restrict__ features, __bf16* __restrict__ fbf,
    const float* __restrict__ W0, const float* __restrict__ Wres0, __bf16* __restrict__ Bt0,
    const float* __restrict__ W1, __bf16* __restrict__ Bt1,
    const float* __restrict__ We0, const float* __restrict__ ae0, float* __restrict__ Ve0,
    const float* __restrict__ We1, const float* __restrict__ ae1, float* __restrict__ Ve1,
    const int* __restrict__ dst, int* __restrict__ cnt) {
  int b = blockIdx.x;
  int t = threadIdx.x;
  if (b < 1563) {                       // fp32 -> bf16, 8 elems/thread
    int i = b * 256 + t;
    if (i < NN * 64 / 8) {
      const float4* p = (const float4*)features + (size_t)i * 2;
      float4 a = p[0], c = p[1];
      bf16_8 v = {(__bf16)a.x, (__bf16)a.y, (__bf16)a.z, (__bf16)a.w,
                  (__bf16)c.x, (__bf16)c.y, (__bf16)c.z, (__bf16)c.w};
      *(bf16_8*)(fbf + (size_t)i * 8) = v;
    }
  } else if (b < 1563 + 128) {          // Bt0 (512x64): W0^T | Wres0^T
    int idx = (b - 1563) * 256 + t;
    int j = idx >> 6, k = idx & 63;
    float v = (j < 256) ? W0[k * 256 + j] : Wres0[k * 256 + (j - 256)];
    Bt0[idx] = (__bf16)v;
  } else if (b < 1563 + 128 + 256) {    // Bt1 (256x256) = W1^T
    int idx = (b - 1563 - 128) * 256 + t;
    int j = idx >> 8, k = idx & 255;
    Bt1[idx] = (__bf16)W1[k * 256 + j];
  } else if (b == 1947) {               // Ve0
    int f = t >> 2, h = t & 3;
    float s = 0.f;
    for (int d = 0; d < 64; ++d) s += We0[f * 256 + h * 64 + d] * ae0[h * 64 + d];
    Ve0[f * 4 + h] = s;
  } else if (b == 1948) {               // Ve1
    int f = t >> 2, h = t & 3;
    float s = 0.f;
    for (int d = 0; d < 64; ++d) s += We1[f * 256 + h * 64 + d] * ae1[h * 64 + d];
    Ve1[f * 4 + h] = s;
  } else {                              // degree count
    int e = (b - 1949) * 256 + t;
    if (e < EE) atomicAdd(&cnt[dst[e]], 1);
  }
}

// ---------------------------------------------------------------- CSR scan (3-phase)
__global__ __launch_bounds__(256) void scan1_kernel(const int* __restrict__ cnt,
                                                    int* __restrict__ scanbuf,
                                                    int* __restrict__ blocksum) {
  __shared__ int s[256];
  int t = threadIdx.x;
  int idx = blockIdx.x * 256 + t;
  int c = (idx < NN) ? cnt[idx] : 0;
  s[t] = c;
  __syncthreads();
  for (int d = 1; d < 256; d <<= 1) {
    int v = (t >= d) ? s[t - d] : 0;
    __syncthreads();
    s[t] += v;
    __syncthreads();
  }
  if (idx < NN) scanbuf[idx] = s[t];
  if (t == 255) blocksum[blockIdx.x] = s[255];
}

__global__ __launch_bounds__(256) void scan2_kernel(const int* __restrict__ blocksum,
                                                    int* __restrict__ blockoff, int nb) {
  __shared__ int s[256];
  int t = threadIdx.x;
  int c = (t < nb) ? blocksum[t] : 0;
  s[t] = c;
  __syncthreads();
  for (int d = 1; d < 256; d <<= 1) {
    int v = (t >= d) ? s[t - d] : 0;
    __syncthreads();
    s[t] += v;
    __syncthreads();
  }
  if (t < nb) blockoff[t] = s[t] - c;  // exclusive
}

__global__ __launch_bounds__(256) void scan3_kernel(const int* __restrict__ scanbuf,
                                                    const int* __restrict__ cnt,
                                                    const int* __restrict__ blockoff,
                                                    int* __restrict__ off,
                                                    int* __restrict__ cur) {
  int idx = blockIdx.x * 256 + threadIdx.x;
  if (idx < NN) {
    int o = blockoff[blockIdx.x] + scanbuf[idx] - cnt[idx];
    off[idx] = o;
    cur[idx] = o;
  }
  if (idx == 0) off[NN] = EE;
}

// records src_csr[p] and eid_csr[p]
__global__ __launch_bounds__(256) void fill_kernel(const int* __restrict__ src,
                                                   const int* __restrict__ dst,
                                                   int* __restrict__ cur,
                                                   int* __restrict__ srcc,
                                                   int* __restrict__ eidc) {
  int e = blockIdx.x * 256 + threadIdx.x;
  if (e < EE) {
    int p = atomicAdd(&cur[dst[e]], 1);
    srcc[p] = src[e];
    eidc[p] = e;
  }
}

// ---------------------------------------------------------------- edge ee pass
// eeo[e*8 + {0..3}] = ef[e].Ve0 (heads), eeo[e*8 + {4..7}] = ef[e].Ve1.
// 4 lanes per row: 64B-contiguous segments per load instr; coalesced writes.
__global__ __launch_bounds__(256) void eek_kernel(const float* __restrict__ ef,
                                                  const float* __restrict__ Ve0,
                                                  const float* __restrict__ Ve1,
                                                  float* __restrict__ eeo) {
  __shared__ float V0[256], V1[256];
  V0[threadIdx.x] = Ve0[threadIdx.x];
  V1[threadIdx.x] = Ve1[threadIdx.x];
  __syncthreads();
  int r = threadIdx.x >> 2, sub = threadIdx.x & 3;
  int e = blockIdx.x * 64 + r;
  if (e >= EE) return;
  float a0 = 0, a1 = 0, a2 = 0, a3 = 0;
  float c0 = 0, c1 = 0, c2 = 0, c3 = 0;
  const float* row = ef + (size_t)e * 64 + sub * 16;
#pragma unroll
  for (int i = 0; i < 16; i += 4) {
    float4 v = *(const float4*)(row + i);
    float xs[4] = {v.x, v.y, v.z, v.w};
#pragma unroll
    for (int j = 0; j < 4; ++j) {
      float x = xs[j];
      int idx = (sub * 16 + i + j) * 4;
      a0 += x * V0[idx + 0]; a1 += x * V0[idx + 1];
      a2 += x * V0[idx + 2]; a3 += x * V0[idx + 3];
      c0 += x * V1[idx + 0]; c1 += x * V1[idx + 1];
      c2 += x * V1[idx + 2]; c3 += x * V1[idx + 3];
    }
  }
#pragma unroll
  for (int o = 1; o < 4; o <<= 1) {
    a0 += __shfl_xor(a0, o); a1 += __shfl_xor(a1, o);
    a2 += __shfl_xor(a2, o); a3 += __shfl_xor(a3, o);
    c0 += __shfl_xor(c0, o); c1 += __shfl_xor(c1, o);
    c2 += __shfl_xor(c2, o); c3 += __shfl_xor(c3, o);
  }
  if (sub == 0) {
    float4 u; u.x = a0; u.y = a1; u.z = a2; u.w = a3;
    float4 w; w.x = c0; w.y = c1; w.z = c2; w.w = c3;
    *(float4*)(eeo + (size_t)e * 8) = u;
    *(float4*)(eeo + (size_t)e * 8 + 4) = w;
  }
}

// ---------------------------------------------------------------- MFMA GEMM
// C[M x NC] = A @ B, Bt: NC x K row-major. cols<256 -> ft (bf16) + fused el/er;
// cols>=256 -> base = val + bias[col-256] (layer 0 residual).
#define LDK 40
__global__ __launch_bounds__(256) void gemm_kernel(const __bf16* __restrict__ A,
                                                   const __bf16* __restrict__ Bt,
                                                   __bf16* __restrict__ ft,
                                                   __bf16* __restrict__ base,
                                                   const float* __restrict__ bias,
                                                   const float* __restrict__ al,
                                                   const float* __restrict__ ar,
                                                   float* __restrict__ el,
                                                   float* __restrict__ er,
                                                   int M, int K) {
  __shared__ __align__(16) __bf16 Al[64 * LDK];
  __shared__ __align__(16) __bf16 Bl[64 * LDK];
  int tid = threadIdx.x;
  int wav = tid >> 6, lane = tid & 63;
  int quad = lane >> 4, l16 = lane & 15;
  int bm = blockIdx.x * 64;
  int bn = blockIdx.y * 64;
  int sr = tid >> 2;
  int sk = (tid & 3) << 3;

  f32x4 acc[4] = {{0, 0, 0, 0}, {0, 0, 0, 0}, {0, 0, 0, 0}, {0, 0, 0, 0}};

  for (int k0 = 0; k0 < K; k0 += 32) {
    uint4 av = {0, 0, 0, 0};
    int arow = bm + sr;
    if (arow < M) av = *(const uint4*)(A + (size_t)arow * K + k0 + sk);
    uint4 bv = *(const uint4*)(Bt + (size_t)(bn + sr) * K + k0 + sk);
    __syncthreads();
    *(uint4*)&Al[sr * LDK + sk] = av;
    *(uint4*)&Bl[sr * LDK + sk] = bv;
    __syncthreads();
    bf16_8 af = *(const bf16_8*)&Al[(wav * 16 + l16) * LDK + quad * 8];
#pragma unroll
    for (int nt = 0; nt < 4; ++nt) {
      bf16_8 bf = *(const bf16_8*)&Bl[(nt * 16 + l16) * LDK + quad * 8];
      acc[nt] = __builtin_amdgcn_mfma_f32_16x16x32_bf16(af, bf, acc[nt], 0, 0, 0);
    }
  }

  int row0 = bm + wav * 16 + quad * 4;

  // fused el/er for head hb = bn/64 (cols < 256 only)
  if (bn < 256) {
    int hb = bn >> 6;
#pragma unroll
    for (int r = 0; r < 4; ++r) {
      float pl = 0.f, pr = 0.f;
#pragma unroll
      for (int nt = 0; nt < 4; ++nt) {
        float v = acc[nt][r];
        int d = nt * 16 + l16;
        pl += v * al[hb * 64 + d];
        pr += v * ar[hb * 64 + d];
      }
#pragma unroll
      for (int o2 = 8; o2 > 0; o2 >>= 1) {
        pl += __shfl_xor(pl, o2);
        pr += __shfl_xor(pr, o2);
      }
      int row = row0 + r;
      if (l16 == 0 && row < M) {
        el[row * 4 + hb] = pl;
        er[row * 4 + hb] = pr;
      }
    }
  }

#pragma unroll
  for (int nt = 0; nt < 4; ++nt) {
    int col = bn + nt * 16 + l16;
#pragma unroll
    for (int r = 0; r < 4; ++r) {
      int row = row0 + r;
      if (row < M) {
        float v = acc[nt][r];
        if (col < 256)
          ft[(size_t)row * 256 + col] = (__bf16)v;
        else
          base[(size_t)row * 256 + (col - 256)] = (__bf16)(v + bias[col - 256]);
      }
    }
  }
}

// ---------------------------------------------------------------- agg
// One block per dst node; wave = head. Computes softmax weight inline:
// w = exp(leaky(el[s] + er[n] + eeo[e])) — all wave-uniform loads.
// acc += w*ft[s], den += w. LAYER 0: +prev, ELU -> outb bf16 (aliases prev;
// same-slot RMW). LAYER 1: +prev+bias, mean heads -> outf fp32.
template <int LAYER>
__global__ __launch_bounds__(256) void agg_kernel(const int* __restrict__ off,
                                                  const int* __restrict__ srcc,
                                                  const int* __restrict__ eidc,
                                                  const float* __restrict__ eeo,
                                                  const float* __restrict__ el,
                                                  const float* __restrict__ er,
                                                  const __bf16* __restrict__ ft,
                                                  const __bf16* prev,
                                                  const float* __restrict__ bias,
                                                  __bf16* outb,
                                                  float* __restrict__ outf) {
  __shared__ float red[256];
  int n = blockIdx.x;
  int t = threadIdx.x, h = t >> 6, lane = t & 63;
  int beg = off[n], end = off[n + 1];
  float pv = (float)prev[(size_t)n * 256 + t];
  float bv = (LAYER == 1) ? bias[t] : 0.f;
  float ern = er[n * 4 + h];
  int offd = h * 64 + lane;

  float acc = 0.f, den = 0.f;
  int j = beg;
  for (; j + 4 <= end; j += 4) {
    int s0 = srcc[j], s1 = srcc[j + 1], s2 = srcc[j + 2], s3 = srcc[j + 3];
    int e0 = eidc[j], e1 = eidc[j + 1], e2 = eidc[j + 2], e3 = eidc[j + 3];
    float z0 = el[s0 * 4 + h] + ern + eeo[(size_t)e0 * 8 + LAYER * 4 + h];
    float z1 = el[s1 * 4 + h] + ern + eeo[(size_t)e1 * 8 + LAYER * 4 + h];
    float z2 = el[s2 * 4 + h] + ern + eeo[(size_t)e2 * 8 + LAYER * 4 + h];
    float z3 = el[s3 * 4 + h] + ern + eeo[(size_t)e3 * 8 + LAYER * 4 + h];
    float w0 = __expf(z0 > 0.f ? z0 : 0.2f * z0);
    float w1 = __expf(z1 > 0.f ? z1 : 0.2f * z1);
    float w2 = __expf(z2 > 0.f ? z2 : 0.2f * z2);
    float w3 = __expf(z3 > 0.f ? z3 : 0.2f * z3);
    float v0 = (float)ft[(size_t)s0 * 256 + offd];
    float v1 = (float)ft[(size_t)s1 * 256 + offd];
    float v2 = (float)ft[(size_t)s2 * 256 + offd];
    float v3 = (float)ft[(size_t)s3 * 256 + offd];
    acc += w0 * v0; acc += w1 * v1; acc += w2 * v2; acc += w3 * v3;
    den += w0 + w1 + w2 + w3;
  }
  for (; j < end; ++j) {
    int s = srcc[j];
    float z = el[s * 4 + h] + ern + eeo[(size_t)eidc[j] * 8 + LAYER * 4 + h];
    float w = __expf(z > 0.f ? z : 0.2f * z);
    acc += w * (float)ft[(size_t)s * 256 + offd];
    den += w;
  }
  float res = (end > beg) ? acc / den : 0.f;

  if (LAYER == 0) {
    float v = res + pv;
    v = v > 0.f ? v : (__expf(v) - 1.0f);  // ELU
    outb[(size_t)n * 256 + t] = (__bf16)v;
  } else {
    red[t] = res + pv + bv;
    __syncthreads();
    if (t < 64)
      outf[(size_t)n * 64 + t] =
          0.25f * (red[t] + red[t + 64] + red[t + 128] + red[t + 192]);
  }
}

// ---------------------------------------------------------------- launch
extern "C" void kernel_launch(void* const* d_in, const int* in_sizes, int n_in,
                              void* d_out, int out_size, void* d_ws, size_t ws_size,
                              hipStream_t stream) {
  const float* features  = (const float*)d_in[0];
  const float* edge_feat = (const float*)d_in[1];
  const int*   src       = (const int*)d_in[2];
  const int*   dst       = (const int*)d_in[3];
  const float* W0    = (const float*)d_in[4];
  const float* We0   = (const float*)d_in[5];
  const float* al0   = (const float*)d_in[6];
  const float* ar0   = (const float*)d_in[7];
  const float* ae0   = (const float*)d_in[8];
  const float* b0    = (const float*)d_in[9];
  const float* Wres0 = (const float*)d_in[10];
  const float* W1    = (const float*)d_in[11];
  const float* We1   = (const float*)d_in[12];
  const float* al1   = (const float*)d_in[13];
  const float* ar1   = (const float*)d_in[14];
  const float* ae1   = (const float*)d_in[15];
  const float* b1    = (const float*)d_in[16];
  float* out = (float*)d_out;

  char* ws = (char*)d_ws;
  size_t o = 0;
  auto alloc = [&](size_t bytes) {
    void* p = ws + o;
    o = (o + bytes + 255) & ~(size_t)255;
    return p;
  };
  int*    cnt      = (int*)alloc((size_t)NN * 4);
  int*    scanbuf  = (int*)alloc((size_t)NN * 4);
  int*    blocksum = (int*)alloc(256 * 4);
  int*    blockoff = (int*)alloc(256 * 4);
  int*    off      = (int*)alloc((size_t)(NN + 1) * 4);
  int*    cur      = (int*)alloc((size_t)NN * 4);
  int*    srcc     = (int*)alloc((size_t)EE * 4);
  int*    eidc     = (int*)alloc((size_t)EE * 4);
  float*  eeo      = (float*)alloc((size_t)EE * 8 * 4);
  float*  el       = (float*)alloc((size_t)NN * 4 * 4);
  float*  er       = (float*)alloc((size_t)NN * 4 * 4);
  float*  Ve0      = (float*)alloc(256 * 4);
  float*  Ve1      = (float*)alloc(256 * 4);
  __bf16* Bt0      = (__bf16*)alloc((size_t)512 * 64 * 2);
  __bf16* Bt1      = (__bf16*)alloc((size_t)256 * 256 * 2);
  __bf16* fbf      = (__bf16*)alloc((size_t)NN * 64 * 2);
  __bf16* ft       = (__bf16*)alloc((size_t)NN * 256 * 2);
  __bf16* base     = (__bf16*)alloc((size_t)NN * 256 * 2);  // h1 aliases base
  __bf16* h1       = base;

  const int EB = (EE + 255) / 256;   // 1563
  const int MG = (NN + 63) / 64;     // 782

  hipMemsetAsync(cnt, 0, (size_t)NN * 4, stream);
  prep_kernel<<<1949 + EB, 256, 0, stream>>>(features, fbf, W0, Wres0, Bt0, W1, Bt1,
                                             We0, ae0, Ve0, We1, ae1, Ve1, dst, cnt);
  scan1_kernel<<<NB, 256, 0, stream>>>(cnt, scanbuf, blocksum);
  scan2_kernel<<<1, 256, 0, stream>>>(blocksum, blockoff, NB);
  scan3_kernel<<<NB, 256, 0, stream>>>(scanbuf, cnt, blockoff, off, cur);
  fill_kernel<<<EB, 256, 0, stream>>>(src, dst, cur, srcc, eidc);
  eek_kernel<<<(EE + 63) / 64, 256, 0, stream>>>(edge_feat, Ve0, Ve1, eeo);

  // ---- layer 0
  gemm_kernel<<<dim3(MG, 8), 256, 0, stream>>>(fbf, Bt0, ft, base, b0, al0, ar0, el, er, NN, 64);
  agg_kernel<0><<<NN, 256, 0, stream>>>(off, srcc, eidc, eeo, el, er, ft, base, nullptr, h1, nullptr);

  // ---- layer 1
  gemm_kernel<<<dim3(MG, 4), 256, 0, stream>>>(h1, Bt1, ft, nullptr, nullptr, al1, ar1, el, er, NN, 256);
  agg_kernel<1><<<NN, 256, 0, stream>>>(off, srcc, eidc, eeo, el, er, ft, h1, b1, nullptr, out);
}